// Round 13
// baseline (336.652 us; speedup 1.0000x reference)
//
#include <hip/hip_runtime.h>

#define ED 64
#define HD 4
#define BD 1024
#define SNEG 22222
#define NT2 1408             // padded tile count: 32 blocks x 4 waves x 11 tiles
#define SPAD2 22528          // NT2*16
#define SP1 (SNEG+1)         // 22223
#define LOGQ -3.81776242f    // log(-expm1(S*log1p(-1/V)))
#define LOG2E 1.44269504f
#define PREP 4               // DIAGNOSTIC: k_probs-only inflation

typedef short bf16x8 __attribute__((ext_vector_type(8)));
typedef float f32x4 __attribute__((ext_vector_type(4)));

static __device__ __forceinline__ short f2bf(float f) {
    union { float f; unsigned u; } v; v.f = f;
    return (short)((v.u + 0x7FFFu + ((v.u >> 16) & 1u)) >> 16);
}

static __device__ __forceinline__ float fast_tanh(float x) {
    float ax = __builtin_fabsf(x);
    float e  = __expf(-2.f * ax);
    float t  = (1.f - e) / (1.f + e);
    return __builtin_copysignf(t, x);
}

static __device__ __forceinline__ float fexp2(float x) {
#if __has_builtin(__builtin_amdgcn_exp2f)
    return __builtin_amdgcn_exp2f(x);
#else
    return __expf(x * 0.69314718f);
#endif
}

// ---------------- kernel 1: fused setup (prep + gather + zero denom) ------
__global__ __launch_bounds__(256) void k_setup(
        const float* __restrict__ inputs, const float* __restrict__ emb,
        const float* __restrict__ proj,   const float* __restrict__ mix,
        const float* __restrict__ biases, const int* __restrict__ label,
        const int* __restrict__ sids,
        short* __restrict__ A, float* __restrict__ pi, float* __restrict__ tl,
        short* __restrict__ W, float* __restrict__ bias_s,
        float* __restrict__ denom) {
    if (blockIdx.x < BD) {
        int b = blockIdx.x, t = threadIdx.x;
        __shared__ float s_in[64];
        __shared__ float s_proj[256];
        __shared__ float s_mix[4];
        __shared__ float s_red[256];
        if (t < 64) s_in[t] = inputs[b*64 + t];
        __syncthreads();
        const float* pr = proj + t*64;
        float dot = 0.f;
        #pragma unroll
        for (int k = 0; k < 64; k += 4)
            dot += s_in[k]*pr[k] + s_in[k+1]*pr[k+1] + s_in[k+2]*pr[k+2] + s_in[k+3]*pr[k+3];
        float val = fast_tanh(dot);
        s_proj[t] = val;
        A[(b*4 + (t >> 6))*64 + (t & 63)] = f2bf(val * LOG2E);
        if (t < 4) {
            const float* mr = mix + t*64;
            float md = 0.f;
            for (int k = 0; k < 64; ++k) md += s_in[k]*mr[k];
            s_mix[t] = md;
        }
        int lab = label[b];
        s_red[t] = s_proj[t] * emb[(size_t)lab*64 + (t & 63)];
        __syncthreads();
        if (t < 4) {
            float m = fmaxf(fmaxf(s_mix[0], s_mix[1]), fmaxf(s_mix[2], s_mix[3]));
            float e0 = __expf(s_mix[0]-m), e1 = __expf(s_mix[1]-m);
            float e2 = __expf(s_mix[2]-m), e3 = __expf(s_mix[3]-m);
            pi[b*4 + t] = __expf(s_mix[t]-m) / (e0+e1+e2+e3);
            float sum = 0.f;
            for (int k = 0; k < 64; ++k) sum += s_red[t*64 + k];
            tl[b*4 + t] = (sum + biases[lab] - LOGQ) * LOG2E;
        }
    } else {
        int t = (blockIdx.x - BD)*256 + threadIdx.x;
        if (t < BD*HD) denom[t] = 0.f;
        int s = t >> 3, l8 = t & 7;
        if (s >= SPAD2) return;
        if (s < SNEG) {
            int id = sids[s];
            const float* src = emb + (size_t)id*64 + l8*8;
            bf16x8 o;
            #pragma unroll
            for (int j = 0; j < 8; ++j) o[j] = f2bf(src[j]);
            *(bf16x8*)(W + s*64 + l8*8) = o;
            if (l8 == 0) bias_s[s] = (biases[id] - LOGQ) * LOG2E;
        } else {
            bf16x8 o;
            #pragma unroll
            for (int j = 0; j < 8; ++j) o[j] = 0;
            *(bf16x8*)(W + s*64 + l8*8) = o;
            if (l8 == 0) bias_s[s] = -1e30f;
        }
    }
}

#define LOADT(S, T) { \
    const bf16x8* bp_ = (const bf16x8*)(W + (size_t)((T)*16 + c)*64); \
    b0##S = bp_[g]; b1##S = bp_[4 + g]; bb##S = bias_s[(T)*16 + c]; }

#define DCOMP(S) { \
    _Pragma("unroll") \
    for (int t4 = 0; t4 < 4; ++t4) { \
        f32x4 z = {bb##S, bb##S, bb##S, bb##S}; \
        z = __builtin_amdgcn_mfma_f32_16x16x32_bf16(a0[t4], b0##S, z, 0, 0, 0); \
        z = __builtin_amdgcn_mfma_f32_16x16x32_bf16(a1[t4], b1##S, z, 0, 0, 0); \
        s[t4*4+0] += fexp2(z[0]); \
        s[t4*4+1] += fexp2(z[1]); \
        s[t4*4+2] += fexp2(z[2]); \
        s[t4*4+3] += fexp2(z[3]); } }

#define PCOMPL(S, TL) { \
    _Pragma("unroll") \
    for (int t4 = 0; t4 < 4; ++t4) { \
        f32x4 z = {bb##S, bb##S, bb##S, bb##S}; \
        z = __builtin_amdgcn_mfma_f32_16x16x32_bf16(a0[t4], b0##S, z, 0, 0, 0); \
        z = __builtin_amdgcn_mfma_f32_16x16x32_bf16(a1[t4], b1##S, z, 0, 0, 0); \
        float p_ = cf[t4][0]*fexp2(z[0]); \
        p_ = fmaf(cf[t4][1], fexp2(z[1]), p_); \
        p_ = fmaf(cf[t4][2], fexp2(z[2]), p_); \
        p_ = fmaf(cf[t4][3], fexp2(z[3]), p_); \
        s_out[(t4*4 + g)*705 + (TL)*16 + c] = p_; } }

// ---------------- kernel 2: denominators -----------------------------------
__global__ __launch_bounds__(256, 4) void k_denom(
        const short* __restrict__ A, const short* __restrict__ W,
        const float* __restrict__ bias_s, float* __restrict__ denom) {
    const int wave = threadIdx.x >> 6, lane = threadIdx.x & 63;
    const int g = lane >> 4, c = lane & 15;
    const int rbase = blockIdx.y * 64;
    bf16x8 a0[4], a1[4];
    #pragma unroll
    for (int t4 = 0; t4 < 4; ++t4) {
        const bf16x8* ap = (const bf16x8*)(A + (size_t)(rbase + t4*16 + c)*64);
        a0[t4] = ap[g]; a1[t4] = ap[4 + g];
    }
    float s[16];
    #pragma unroll
    for (int i = 0; i < 16; ++i) s[i] = 0.f;

    const int t0 = (blockIdx.x*4 + wave) * 11;
    bf16x8 b0A, b1A, b0B, b1B, b0C, b1C;
    float bbA, bbB, bbC;
    LOADT(A, t0+0) LOADT(B, t0+1) LOADT(C, t0+2)
    DCOMP(A) LOADT(A, t0+3)
    DCOMP(B) LOADT(B, t0+4)
    DCOMP(C) LOADT(C, t0+5)
    DCOMP(A) LOADT(A, t0+6)
    DCOMP(B) LOADT(B, t0+7)
    DCOMP(C) LOADT(C, t0+8)
    DCOMP(A) LOADT(A, t0+9)
    DCOMP(B) LOADT(B, t0+10)
    DCOMP(C)
    DCOMP(A)
    DCOMP(B)

    #pragma unroll
    for (int m = 1; m < 16; m <<= 1)
        #pragma unroll
        for (int i = 0; i < 16; ++i) s[i] += __shfl_xor(s[i], m);
    if (c == 0) {
        #pragma unroll
        for (int t4 = 0; t4 < 4; ++t4)
            #pragma unroll
            for (int r = 0; r < 4; ++r)
                atomicAdd(&denom[rbase + t4*16 + g*4 + r], s[t4*4+r]);
    }
}

// ---------------- kernel 3: probs, DIAG PREP=4, float4-aligned flush -------
__global__ __launch_bounds__(256, 3) void k_probs(
        const short* __restrict__ A, const short* __restrict__ W,
        const float* __restrict__ bias_s, const float* __restrict__ pi,
        const float* __restrict__ tl, const float* __restrict__ denom,
        float* __restrict__ out) {
    const int t = threadIdx.x;
    const int wave = t >> 6, lane = t & 63;
    const int g = lane >> 4, c = lane & 15;
    const int rbase = blockIdx.y * 64;
    __shared__ float s_cf[64];
    __shared__ float s_et[64];
    __shared__ float s_ls[4];
    __shared__ float s_out[16*705];

    if (t < 64) {
        int row = rbase + t;
        float et = fexp2(tl[row]);
        float d  = denom[row] + et;
        s_cf[t] = pi[row] / d;
        s_et[t] = et;
    }
    __syncthreads();
    if (blockIdx.x == 0 && t < 16) {
        float p0 = 0.f;
        #pragma unroll
        for (int h = 0; h < 4; ++h) p0 += s_cf[t*4 + h] * s_et[t*4 + h];
        out[(size_t)(rbase/4 + t) * SP1] = p0;
    }
    if (blockIdx.x == 0 && blockIdx.y == 0) {
        float lg = 0.f;
        for (int b = t; b < BD; b += 256) {
            float p0 = 0.f;
            #pragma unroll
            for (int h = 0; h < 4; ++h) {
                float et = fexp2(tl[b*4 + h]);
                p0 += pi[b*4 + h] / (denom[b*4 + h] + et) * et;
            }
            lg += logf(p0);
        }
        #pragma unroll
        for (int m = 1; m < 64; m <<= 1) lg += __shfl_xor(lg, m);
        if (lane == 0) s_ls[wave] = lg;
        __syncthreads();
        if (t == 0)
            out[(size_t)BD * SP1] = -(s_ls[0]+s_ls[1]+s_ls[2]+s_ls[3]) * (1.f/(float)BD);
    }

    bf16x8 a0[4], a1[4];
    float cf[4][4];
    #pragma unroll
    for (int t4 = 0; t4 < 4; ++t4) {
        const bf16x8* ap = (const bf16x8*)(A + (size_t)(rbase + t4*16 + c)*64);
        a0[t4] = ap[g]; a1[t4] = ap[4 + g];
        #pragma unroll
        for (int r = 0; r < 4; ++r) cf[t4][r] = s_cf[t4*16 + g*4 + r];
    }

    const int t0  = (blockIdx.x*4 + wave) * 11;
    const int tl0 = wave * 11;
    const int colbase = blockIdx.x * 704;
    const int browbase = rbase >> 2;
    int nvalid = SNEG - colbase; if (nvalid > 704) nvalid = 704;
    bf16x8 b0A, b1A, b0B, b1B, b0C, b1C;
    float bbA, bbB, bbC;

    #pragma unroll 1
    for (int rep = 0; rep < PREP; ++rep) {       // DIAG: idempotent full-body reps
        LOADT(A, t0+0) LOADT(B, t0+1) LOADT(C, t0+2)
        PCOMPL(A, tl0+0)  LOADT(A, t0+3)
        PCOMPL(B, tl0+1)  LOADT(B, t0+4)
        PCOMPL(C, tl0+2)  LOADT(C, t0+5)
        PCOMPL(A, tl0+3)  LOADT(A, t0+6)
        PCOMPL(B, tl0+4)  LOADT(B, t0+7)
        PCOMPL(C, tl0+5)  LOADT(C, t0+8)
        PCOMPL(A, tl0+6)  LOADT(A, t0+9)
        PCOMPL(B, tl0+7)  LOADT(B, t0+10)
        PCOMPL(C, tl0+8)
        PCOMPL(A, tl0+9)
        PCOMPL(B, tl0+10)
        __syncthreads();
        // flush: wave w owns rows 4w..4w+3; scalar head to 16B alignment, then
        // dwordx4 body (the 7 TB/s fill pattern), scalar tail.
        #pragma unroll
        for (int j = 0; j < 4; ++j) {
            int r = wave*4 + j;
            float* dst = out + (size_t)(browbase + r)*SP1 + 1 + colbase;
            const float* src = &s_out[r*705];
            int off = (int)(((size_t)dst >> 2) & 3);
            int h = (4 - off) & 3; if (h > nvalid) h = nvalid;
            if (lane < h) dst[lane] = src[lane];
            int nb = (nvalid - h) >> 2;
            float4* d4 = (float4*)(dst + h);
            for (int k = lane; k < nb; k += 64) {
                const float* sp = src + h + 4*k;
                float4 v = make_float4(sp[0], sp[1], sp[2], sp[3]);
                d4[k] = v;
            }
            for (int k = h + nb*4 + lane; k < nvalid; k += 64) dst[k] = src[k];
        }
        __syncthreads();
        asm volatile("" ::: "memory");
    }
}

extern "C" void kernel_launch(void* const* d_in, const int* in_sizes, int n_in,
                              void* d_out, int out_size, void* d_ws, size_t ws_size,
                              hipStream_t stream) {
    const float* inputs = (const float*)d_in[0];
    const float* emb    = (const float*)d_in[1];
    const float* proj   = (const float*)d_in[2];
    const float* mix    = (const float*)d_in[3];
    const float* biases = (const float*)d_in[4];
    const int*   label  = (const int*)d_in[5];
    const int*   sids   = (const int*)d_in[6];
    float* out = (float*)d_out;

    char* ws = (char*)d_ws;
    short* W      = (short*)(ws);                      // 2,883,584 B
    short* A      = (short*)(ws + 2883584);            // 524,288 B
    float* bias_s = (float*)(ws + 3407872);            // 90,112 B
    float* denom  = (float*)(ws + 3497984);            // 16,384 B
    float* pi     = (float*)(ws + 3514368);            // 16,384 B
    float* tl     = (float*)(ws + 3530752);            // 16,384 B

    int gather_blocks = (SPAD2*8) / 256;               // 704
    k_setup<<<BD + gather_blocks, 256, 0, stream>>>(
        inputs, emb, proj, mix, biases, label, sids, A, pi, tl, W, bias_s, denom);
    k_denom<<<dim3(32, 64), 256, 0, stream>>>(A, W, bias_s, denom);
    k_probs<<<dim3(32, 64), 256, 0, stream>>>(A, W, bias_s, pi, tl, denom, out);
}

// Round 14
// 108.633 us; speedup vs baseline: 3.0990x; 3.0990x over previous
//
#include <hip/hip_runtime.h>

#define ED 64
#define HD 4
#define BD 1024
#define SNEG 22222
#define NT2 1408             // padded tile count: 32 blocks x 4 waves x 11 tiles
#define SPAD2 22528          // NT2*16
#define SP1 (SNEG+1)         // 22223
#define LOGQ -3.81776242f    // log(-expm1(S*log1p(-1/V)))
#define LOG2E 1.44269504f

typedef short bf16x8 __attribute__((ext_vector_type(8)));
typedef float f32x4 __attribute__((ext_vector_type(4)));

static __device__ __forceinline__ short f2bf(float f) {
    union { float f; unsigned u; } v; v.f = f;
    return (short)((v.u + 0x7FFFu + ((v.u >> 16) & 1u)) >> 16);
}

static __device__ __forceinline__ float fast_tanh(float x) {
    float ax = __builtin_fabsf(x);
    float e  = __expf(-2.f * ax);
    float t  = (1.f - e) / (1.f + e);
    return __builtin_copysignf(t, x);
}

static __device__ __forceinline__ float fexp2(float x) {
#if __has_builtin(__builtin_amdgcn_exp2f)
    return __builtin_amdgcn_exp2f(x);
#else
    return __expf(x * 0.69314718f);
#endif
}

// ---------------- kernel 1: fused setup (prep + gather + zero denom) ------
__global__ __launch_bounds__(256) void k_setup(
        const float* __restrict__ inputs, const float* __restrict__ emb,
        const float* __restrict__ proj,   const float* __restrict__ mix,
        const float* __restrict__ biases, const int* __restrict__ label,
        const int* __restrict__ sids,
        short* __restrict__ A, float* __restrict__ pi, float* __restrict__ tl,
        short* __restrict__ W, float* __restrict__ bias_s,
        float* __restrict__ denom) {
    if (blockIdx.x < BD) {
        int b = blockIdx.x, t = threadIdx.x;
        __shared__ float s_in[64];
        __shared__ float s_proj[256];
        __shared__ float s_mix[4];
        __shared__ float s_red[256];
        if (t < 64) s_in[t] = inputs[b*64 + t];
        __syncthreads();
        const float* pr = proj + t*64;
        float dot = 0.f;
        #pragma unroll
        for (int k = 0; k < 64; k += 4)
            dot += s_in[k]*pr[k] + s_in[k+1]*pr[k+1] + s_in[k+2]*pr[k+2] + s_in[k+3]*pr[k+3];
        float val = fast_tanh(dot);
        s_proj[t] = val;
        A[(b*4 + (t >> 6))*64 + (t & 63)] = f2bf(val * LOG2E);
        if (t < 4) {
            const float* mr = mix + t*64;
            float md = 0.f;
            for (int k = 0; k < 64; ++k) md += s_in[k]*mr[k];
            s_mix[t] = md;
        }
        int lab = label[b];
        s_red[t] = s_proj[t] * emb[(size_t)lab*64 + (t & 63)];
        __syncthreads();
        if (t < 4) {
            float m = fmaxf(fmaxf(s_mix[0], s_mix[1]), fmaxf(s_mix[2], s_mix[3]));
            float e0 = __expf(s_mix[0]-m), e1 = __expf(s_mix[1]-m);
            float e2 = __expf(s_mix[2]-m), e3 = __expf(s_mix[3]-m);
            pi[b*4 + t] = __expf(s_mix[t]-m) / (e0+e1+e2+e3);
            float sum = 0.f;
            for (int k = 0; k < 64; ++k) sum += s_red[t*64 + k];
            tl[b*4 + t] = (sum + biases[lab] - LOGQ) * LOG2E;
        }
    } else {
        int t = (blockIdx.x - BD)*256 + threadIdx.x;
        if (t < BD*HD) denom[t] = 0.f;
        int s = t >> 3, l8 = t & 7;
        if (s >= SPAD2) return;
        if (s < SNEG) {
            int id = sids[s];
            const float* src = emb + (size_t)id*64 + l8*8;
            bf16x8 o;
            #pragma unroll
            for (int j = 0; j < 8; ++j) o[j] = f2bf(src[j]);
            *(bf16x8*)(W + s*64 + l8*8) = o;
            if (l8 == 0) bias_s[s] = (biases[id] - LOGQ) * LOG2E;
        } else {
            bf16x8 o;
            #pragma unroll
            for (int j = 0; j < 8; ++j) o[j] = 0;
            *(bf16x8*)(W + s*64 + l8*8) = o;
            if (l8 == 0) bias_s[s] = -1e30f;
        }
    }
}

#define LOADT(S, T) { \
    const bf16x8* bp_ = (const bf16x8*)(W + (size_t)((T)*16 + c)*64); \
    b0##S = bp_[g]; b1##S = bp_[4 + g]; bb##S = bias_s[(T)*16 + c]; }

#define DCOMP(S) { \
    _Pragma("unroll") \
    for (int t4 = 0; t4 < 4; ++t4) { \
        f32x4 z = {bb##S, bb##S, bb##S, bb##S}; \
        z = __builtin_amdgcn_mfma_f32_16x16x32_bf16(a0[t4], b0##S, z, 0, 0, 0); \
        z = __builtin_amdgcn_mfma_f32_16x16x32_bf16(a1[t4], b1##S, z, 0, 0, 0); \
        s[t4*4+0] += fexp2(z[0]); \
        s[t4*4+1] += fexp2(z[1]); \
        s[t4*4+2] += fexp2(z[2]); \
        s[t4*4+3] += fexp2(z[3]); } }

#define PCOMPL(S, TL) { \
    _Pragma("unroll") \
    for (int t4 = 0; t4 < 4; ++t4) { \
        f32x4 z = {bb##S, bb##S, bb##S, bb##S}; \
        z = __builtin_amdgcn_mfma_f32_16x16x32_bf16(a0[t4], b0##S, z, 0, 0, 0); \
        z = __builtin_amdgcn_mfma_f32_16x16x32_bf16(a1[t4], b1##S, z, 0, 0, 0); \
        float p_ = cf[t4][0]*fexp2(z[0]); \
        p_ = fmaf(cf[t4][1], fexp2(z[1]), p_); \
        p_ = fmaf(cf[t4][2], fexp2(z[2]), p_); \
        p_ = fmaf(cf[t4][3], fexp2(z[3]), p_); \
        s_out[(t4*4 + g)*705 + (TL)*16 + c] = p_; } }

// ---------------- kernel 2: denominators -----------------------------------
__global__ __launch_bounds__(256, 4) void k_denom(
        const short* __restrict__ A, const short* __restrict__ W,
        const float* __restrict__ bias_s, float* __restrict__ denom) {
    const int wave = threadIdx.x >> 6, lane = threadIdx.x & 63;
    const int g = lane >> 4, c = lane & 15;
    const int rbase = blockIdx.y * 64;
    bf16x8 a0[4], a1[4];
    #pragma unroll
    for (int t4 = 0; t4 < 4; ++t4) {
        const bf16x8* ap = (const bf16x8*)(A + (size_t)(rbase + t4*16 + c)*64);
        a0[t4] = ap[g]; a1[t4] = ap[4 + g];
    }
    float s[16];
    #pragma unroll
    for (int i = 0; i < 16; ++i) s[i] = 0.f;

    const int t0 = (blockIdx.x*4 + wave) * 11;
    bf16x8 b0A, b1A, b0B, b1B, b0C, b1C;
    float bbA, bbB, bbC;
    LOADT(A, t0+0) LOADT(B, t0+1) LOADT(C, t0+2)
    DCOMP(A) LOADT(A, t0+3)
    DCOMP(B) LOADT(B, t0+4)
    DCOMP(C) LOADT(C, t0+5)
    DCOMP(A) LOADT(A, t0+6)
    DCOMP(B) LOADT(B, t0+7)
    DCOMP(C) LOADT(C, t0+8)
    DCOMP(A) LOADT(A, t0+9)
    DCOMP(B) LOADT(B, t0+10)
    DCOMP(C)
    DCOMP(A)
    DCOMP(B)

    #pragma unroll
    for (int m = 1; m < 16; m <<= 1)
        #pragma unroll
        for (int i = 0; i < 16; ++i) s[i] += __shfl_xor(s[i], m);
    if (c == 0) {
        #pragma unroll
        for (int t4 = 0; t4 < 4; ++t4)
            #pragma unroll
            for (int r = 0; r < 4; ++r)
                atomicAdd(&denom[rbase + t4*16 + g*4 + r], s[t4*4+r]);
    }
}

// ---------------- kernel 3: probs (LDS-staged NT flush) + out[:,0] + loss --
__global__ __launch_bounds__(256, 3) void k_probs(
        const short* __restrict__ A, const short* __restrict__ W,
        const float* __restrict__ bias_s, const float* __restrict__ pi,
        const float* __restrict__ tl, const float* __restrict__ denom,
        float* __restrict__ out) {
    const int t = threadIdx.x;
    const int wave = t >> 6, lane = t & 63;
    const int g = lane >> 4, c = lane & 15;
    const int rbase = blockIdx.y * 64;
    __shared__ float s_cf[64];
    __shared__ float s_et[64];
    __shared__ float s_ls[4];
    __shared__ float s_out[16*705];

    if (t < 64) {
        int row = rbase + t;
        float et = fexp2(tl[row]);
        float d  = denom[row] + et;
        s_cf[t] = pi[row] / d;
        s_et[t] = et;
    }
    __syncthreads();
    if (blockIdx.x == 0 && t < 16) {
        float p0 = 0.f;
        #pragma unroll
        for (int h = 0; h < 4; ++h) p0 += s_cf[t*4 + h] * s_et[t*4 + h];
        out[(size_t)(rbase/4 + t) * SP1] = p0;
    }
    if (blockIdx.x == 0 && blockIdx.y == 0) {
        float lg = 0.f;
        for (int b = t; b < BD; b += 256) {
            float p0 = 0.f;
            #pragma unroll
            for (int h = 0; h < 4; ++h) {
                float et = fexp2(tl[b*4 + h]);
                p0 += pi[b*4 + h] / (denom[b*4 + h] + et) * et;
            }
            lg += logf(p0);
        }
        #pragma unroll
        for (int m = 1; m < 64; m <<= 1) lg += __shfl_xor(lg, m);
        if (lane == 0) s_ls[wave] = lg;
        __syncthreads();
        if (t == 0)
            out[(size_t)BD * SP1] = -(s_ls[0]+s_ls[1]+s_ls[2]+s_ls[3]) * (1.f/(float)BD);
    }

    bf16x8 a0[4], a1[4];
    float cf[4][4];
    #pragma unroll
    for (int t4 = 0; t4 < 4; ++t4) {
        const bf16x8* ap = (const bf16x8*)(A + (size_t)(rbase + t4*16 + c)*64);
        a0[t4] = ap[g]; a1[t4] = ap[4 + g];
        #pragma unroll
        for (int r = 0; r < 4; ++r) cf[t4][r] = s_cf[t4*16 + g*4 + r];
    }

    const int t0  = (blockIdx.x*4 + wave) * 11;
    const int tl0 = wave * 11;
    bf16x8 b0A, b1A, b0B, b1B, b0C, b1C;
    float bbA, bbB, bbC;
    LOADT(A, t0+0) LOADT(B, t0+1) LOADT(C, t0+2)
    PCOMPL(A, tl0+0)  LOADT(A, t0+3)
    PCOMPL(B, tl0+1)  LOADT(B, t0+4)
    PCOMPL(C, tl0+2)  LOADT(C, t0+5)
    PCOMPL(A, tl0+3)  LOADT(A, t0+6)
    PCOMPL(B, tl0+4)  LOADT(B, t0+7)
    PCOMPL(C, tl0+5)  LOADT(C, t0+8)
    PCOMPL(A, tl0+6)  LOADT(A, t0+9)
    PCOMPL(B, tl0+7)  LOADT(B, t0+10)
    PCOMPL(C, tl0+8)
    PCOMPL(A, tl0+9)
    PCOMPL(B, tl0+10)

    __syncthreads();
    // NT flush: consecutive lanes -> consecutive addresses (256 B per wave
    // instruction, sector-complete) and nontemporal (no read-allocate fetch,
    // no L2 eviction-pressure write amp). LDS reads: consecutive banks, free.
    const int colbase = blockIdx.x * 704;
    const int browbase = rbase >> 2;
    #pragma unroll 4
    for (int i = 0; i < 44; ++i) {
        int idx = i*256 + t;                       // 0..11263 = 16*704
        int lb  = idx / 704;
        int col = idx - lb*704;
        int scol = colbase + col;
        if (scol < SNEG)
            __builtin_nontemporal_store(s_out[lb*705 + col],
                                        &out[(size_t)(browbase + lb)*SP1 + 1 + scol]);
    }
}

extern "C" void kernel_launch(void* const* d_in, const int* in_sizes, int n_in,
                              void* d_out, int out_size, void* d_ws, size_t ws_size,
                              hipStream_t stream) {
    const float* inputs = (const float*)d_in[0];
    const float* emb    = (const float*)d_in[1];
    const float* proj   = (const float*)d_in[2];
    const float* mix    = (const float*)d_in[3];
    const float* biases = (const float*)d_in[4];
    const int*   label  = (const int*)d_in[5];
    const int*   sids   = (const int*)d_in[6];
    float* out = (float*)d_out;

    char* ws = (char*)d_ws;
    short* W      = (short*)(ws);                      // 2,883,584 B
    short* A      = (short*)(ws + 2883584);            // 524,288 B
    float* bias_s = (float*)(ws + 3407872);            // 90,112 B
    float* denom  = (float*)(ws + 3497984);            // 16,384 B
    float* pi     = (float*)(ws + 3514368);            // 16,384 B
    float* tl     = (float*)(ws + 3530752);            // 16,384 B

    int gather_blocks = (SPAD2*8) / 256;               // 704
    k_setup<<<BD + gather_blocks, 256, 0, stream>>>(
        inputs, emb, proj, mix, biases, label, sids, A, pi, tl, W, bias_s, denom);
    k_denom<<<dim3(32, 64), 256, 0, stream>>>(A, W, bias_s, denom);
    k_probs<<<dim3(32, 64), 256, 0, stream>>>(A, W, bias_s, pi, tl, denom, out);
}

// Round 15
// 88.598 us; speedup vs baseline: 3.7998x; 1.2261x over previous
//
#include <hip/hip_runtime.h>

#define ED 64
#define HD 4
#define BD 1024
#define SNEG 22222
#define NT2 1408             // 16 col-groups x 88 tiles (4 waves x 22)
#define SPAD2 22528          // NT2*16 = 512 gather blocks x 44 rows
#define SP1 (SNEG+1)         // 22223
#define LOGQ -3.81776242f    // log(-expm1(S*log1p(-1/V)))
#define LOG2E 1.44269504f

typedef short bf16x8 __attribute__((ext_vector_type(8)));
typedef float f32x4 __attribute__((ext_vector_type(4)));

static __device__ __forceinline__ short f2bf(float f) {
    union { float f; unsigned u; } v; v.f = f;
    return (short)((v.u + 0x7FFFu + ((v.u >> 16) & 1u)) >> 16);
}

static __device__ __forceinline__ float fast_tanh(float x) {
    float ax = __builtin_fabsf(x);
    float e  = __expf(-2.f * ax);
    float t  = (1.f - e) / (1.f + e);
    return __builtin_copysignf(t, x);
}

static __device__ __forceinline__ float fexp2(float x) {
#if __has_builtin(__builtin_amdgcn_exp2f)
    return __builtin_amdgcn_exp2f(x);
#else
    return __expf(x * 0.69314718f);
#endif
}

// ---------------- kernel 1: fused setup, 512 blocks ------------------------
// block: prep for batches {2*blk, 2*blk+1} + gather rows [44*blk, 44*blk+44)
__global__ __launch_bounds__(256) void k_setup(
        const float* __restrict__ inputs, const float* __restrict__ emb,
        const float* __restrict__ proj,   const float* __restrict__ mix,
        const float* __restrict__ biases, const int* __restrict__ label,
        const int* __restrict__ sids,
        short* __restrict__ A, float* __restrict__ pi, float* __restrict__ tl,
        short* __restrict__ W, float* __restrict__ bias_s,
        float* __restrict__ denom) {
    const int blk = blockIdx.x, t = threadIdx.x;
    __shared__ float s_in[64];
    __shared__ float s_proj[256];
    __shared__ float s_mix[4];
    __shared__ float s_red[256];

    if (t < 8) denom[blk*8 + t] = 0.f;

    #pragma unroll 1
    for (int bi = 0; bi < 2; ++bi) {
        int b = blk*2 + bi;
        if (t < 64) s_in[t] = inputs[b*64 + t];
        __syncthreads();
        const float* pr = proj + t*64;
        float dot = 0.f;
        #pragma unroll
        for (int k = 0; k < 64; k += 4)
            dot += s_in[k]*pr[k] + s_in[k+1]*pr[k+1] + s_in[k+2]*pr[k+2] + s_in[k+3]*pr[k+3];
        float val = fast_tanh(dot);
        s_proj[t] = val;
        A[(b*4 + (t >> 6))*64 + (t & 63)] = f2bf(val * LOG2E);   // pre-scaled
        if (t < 4) {
            const float* mr = mix + t*64;
            float md = 0.f;
            for (int k = 0; k < 64; ++k) md += s_in[k]*mr[k];
            s_mix[t] = md;
        }
        int lab = label[b];
        s_red[t] = s_proj[t] * emb[(size_t)lab*64 + (t & 63)];
        __syncthreads();
        if (t < 4) {
            float m = fmaxf(fmaxf(s_mix[0], s_mix[1]), fmaxf(s_mix[2], s_mix[3]));
            float e0 = __expf(s_mix[0]-m), e1 = __expf(s_mix[1]-m);
            float e2 = __expf(s_mix[2]-m), e3 = __expf(s_mix[3]-m);
            pi[b*4 + t] = __expf(s_mix[t]-m) / (e0+e1+e2+e3);
            float sum = 0.f;
            for (int k = 0; k < 64; ++k) sum += s_red[t*64 + k];
            tl[b*4 + t] = (sum + biases[lab] - LOGQ) * LOG2E;    // base-2
        }
        __syncthreads();
    }

    // gather: 44 rows x 8 threads = 352 tasks
    #pragma unroll 1
    for (int rep = 0; rep < 2; ++rep) {
        int task = rep*256 + t;
        if (task >= 352) break;
        int s = blk*44 + (task >> 3);
        int l8 = task & 7;
        if (s < SNEG) {
            int id = sids[s];
            const float* src = emb + (size_t)id*64 + l8*8;
            bf16x8 o;
            #pragma unroll
            for (int j = 0; j < 8; ++j) o[j] = f2bf(src[j]);
            *(bf16x8*)(W + s*64 + l8*8) = o;
            if (l8 == 0) bias_s[s] = (biases[id] - LOGQ) * LOG2E;
        } else {
            bf16x8 o;
            #pragma unroll
            for (int j = 0; j < 8; ++j) o[j] = 0;
            *(bf16x8*)(W + s*64 + l8*8) = o;
            if (l8 == 0) bias_s[s] = -1e30f;   // 2^x -> 0 for pad columns
        }
    }
}

#define LOADT(S, T) { \
    const bf16x8* bp_ = (const bf16x8*)(W + (size_t)((T)*16 + c)*64); \
    b0##S = bp_[g]; b1##S = bp_[4 + g]; bb##S = bias_s[(T)*16 + c]; }

#define DCOMP(S) { \
    _Pragma("unroll") \
    for (int t4 = 0; t4 < 4; ++t4) { \
        f32x4 z = {bb##S, bb##S, bb##S, bb##S}; \
        z = __builtin_amdgcn_mfma_f32_16x16x32_bf16(a0[t4], b0##S, z, 0, 0, 0); \
        z = __builtin_amdgcn_mfma_f32_16x16x32_bf16(a1[t4], b1##S, z, 0, 0, 0); \
        s[t4*4+0] += fexp2(z[0]); \
        s[t4*4+1] += fexp2(z[1]); \
        s[t4*4+2] += fexp2(z[2]); \
        s[t4*4+3] += fexp2(z[3]); } }

#define PCOMP(S, T) { \
    int scol_ = (T)*16 + c; bool ok_ = scol_ < SNEG; \
    _Pragma("unroll") \
    for (int t4 = 0; t4 < 4; ++t4) { \
        f32x4 z = {bb##S, bb##S, bb##S, bb##S}; \
        z = __builtin_amdgcn_mfma_f32_16x16x32_bf16(a0[t4], b0##S, z, 0, 0, 0); \
        z = __builtin_amdgcn_mfma_f32_16x16x32_bf16(a1[t4], b1##S, z, 0, 0, 0); \
        float p_ = cf[t4][0]*fexp2(z[0]); \
        p_ = fmaf(cf[t4][1], fexp2(z[1]), p_); \
        p_ = fmaf(cf[t4][2], fexp2(z[2]), p_); \
        p_ = fmaf(cf[t4][3], fexp2(z[3]), p_); \
        if (ok_) orow[t4][scol_] = p_; } }

// 11-step 3-slot rotating pipeline over tiles [TB, TB+11)
#define DPIPE(TB) { \
    LOADT(A, (TB)+0) LOADT(B, (TB)+1) LOADT(C, (TB)+2) \
    DCOMP(A) LOADT(A, (TB)+3) \
    DCOMP(B) LOADT(B, (TB)+4) \
    DCOMP(C) LOADT(C, (TB)+5) \
    DCOMP(A) LOADT(A, (TB)+6) \
    DCOMP(B) LOADT(B, (TB)+7) \
    DCOMP(C) LOADT(C, (TB)+8) \
    DCOMP(A) LOADT(A, (TB)+9) \
    DCOMP(B) LOADT(B, (TB)+10) \
    DCOMP(C) \
    DCOMP(A) \
    DCOMP(B) }

#define PPIPE(TB) { \
    LOADT(A, (TB)+0) LOADT(B, (TB)+1) LOADT(C, (TB)+2) \
    PCOMP(A, (TB)+0)  LOADT(A, (TB)+3) \
    PCOMP(B, (TB)+1)  LOADT(B, (TB)+4) \
    PCOMP(C, (TB)+2)  LOADT(C, (TB)+5) \
    PCOMP(A, (TB)+3)  LOADT(A, (TB)+6) \
    PCOMP(B, (TB)+4)  LOADT(B, (TB)+7) \
    PCOMP(C, (TB)+5)  LOADT(C, (TB)+8) \
    PCOMP(A, (TB)+6)  LOADT(A, (TB)+9) \
    PCOMP(B, (TB)+7)  LOADT(B, (TB)+10) \
    PCOMP(C, (TB)+8) \
    PCOMP(A, (TB)+9) \
    PCOMP(B, (TB)+10) }

// ---------------- kernel 2: denominators, grid (16,64) = 1024 blocks -------
__global__ __launch_bounds__(256, 4) void k_denom(
        const short* __restrict__ A, const short* __restrict__ W,
        const float* __restrict__ bias_s, float* __restrict__ denom) {
    const int wave = threadIdx.x >> 6, lane = threadIdx.x & 63;
    const int g = lane >> 4, c = lane & 15;
    const int rbase = blockIdx.y * 64;
    bf16x8 a0[4], a1[4];
    #pragma unroll
    for (int t4 = 0; t4 < 4; ++t4) {
        const bf16x8* ap = (const bf16x8*)(A + (size_t)(rbase + t4*16 + c)*64);
        a0[t4] = ap[g]; a1[t4] = ap[4 + g];
    }
    float s[16];
    #pragma unroll
    for (int i = 0; i < 16; ++i) s[i] = 0.f;

    const int t0 = (blockIdx.x*4 + wave) * 22;     // 22 contiguous tiles
    bf16x8 b0A, b1A, b0B, b1B, b0C, b1C;
    float bbA, bbB, bbC;
    DPIPE(t0)
    DPIPE(t0 + 11)

    #pragma unroll
    for (int m = 1; m < 16; m <<= 1)
        #pragma unroll
        for (int i = 0; i < 16; ++i) s[i] += __shfl_xor(s[i], m);
    if (c == 0) {
        #pragma unroll
        for (int t4 = 0; t4 < 4; ++t4)
            #pragma unroll
            for (int r = 0; r < 4; ++r)
                atomicAdd(&denom[rbase + t4*16 + g*4 + r], s[t4*4+r]);
    }
}

// ---------------- kernel 3: probs + out[:,0] + loss, grid (16,64) ----------
__global__ __launch_bounds__(256, 4) void k_probs(
        const short* __restrict__ A, const short* __restrict__ W,
        const float* __restrict__ bias_s, const float* __restrict__ pi,
        const float* __restrict__ tl, const float* __restrict__ denom,
        float* __restrict__ out) {
    const int t = threadIdx.x;
    const int wave = t >> 6, lane = t & 63;
    const int g = lane >> 4, c = lane & 15;
    const int rbase = blockIdx.y * 64;
    __shared__ float s_cf[64];
    __shared__ float s_et[64];
    __shared__ float s_ls[4];

    if (t < 64) {
        int row = rbase + t;
        float et = fexp2(tl[row]);
        float d  = denom[row] + et;
        s_cf[t] = pi[row] / d;
        s_et[t] = et;
    }
    __syncthreads();
    if (blockIdx.x == 0 && t < 16) {
        float p0 = 0.f;
        #pragma unroll
        for (int h = 0; h < 4; ++h) p0 += s_cf[t*4 + h] * s_et[t*4 + h];
        out[(size_t)(rbase/4 + t) * SP1] = p0;
    }
    if (blockIdx.x == 0 && blockIdx.y == 0) {
        float lg = 0.f;
        for (int b = t; b < BD; b += 256) {
            float p0 = 0.f;
            #pragma unroll
            for (int h = 0; h < 4; ++h) {
                float et = fexp2(tl[b*4 + h]);
                p0 += pi[b*4 + h] / (denom[b*4 + h] + et) * et;
            }
            lg += logf(p0);
        }
        #pragma unroll
        for (int m = 1; m < 64; m <<= 1) lg += __shfl_xor(lg, m);
        if (lane == 0) s_ls[wave] = lg;
        __syncthreads();
        if (t == 0)
            out[(size_t)BD * SP1] = -(s_ls[0]+s_ls[1]+s_ls[2]+s_ls[3]) * (1.f/(float)BD);
    }

    bf16x8 a0[4], a1[4];
    float cf[4][4];
    float* orow[4];
    #pragma unroll
    for (int t4 = 0; t4 < 4; ++t4) {
        const bf16x8* ap = (const bf16x8*)(A + (size_t)(rbase + t4*16 + c)*64);
        a0[t4] = ap[g]; a1[t4] = ap[4 + g];
        #pragma unroll
        for (int r = 0; r < 4; ++r) cf[t4][r] = s_cf[t4*16 + g*4 + r];
        orow[t4] = out + (size_t)(rbase/4 + t4*4 + g) * SP1 + 1;
    }

    const int t0 = (blockIdx.x*4 + wave) * 22;
    bf16x8 b0A, b1A, b0B, b1B, b0C, b1C;
    float bbA, bbB, bbC;
    PPIPE(t0)
    PPIPE(t0 + 11)
}

extern "C" void kernel_launch(void* const* d_in, const int* in_sizes, int n_in,
                              void* d_out, int out_size, void* d_ws, size_t ws_size,
                              hipStream_t stream) {
    const float* inputs = (const float*)d_in[0];
    const float* emb    = (const float*)d_in[1];
    const float* proj   = (const float*)d_in[2];
    const float* mix    = (const float*)d_in[3];
    const float* biases = (const float*)d_in[4];
    const int*   label  = (const int*)d_in[5];
    const int*   sids   = (const int*)d_in[6];
    float* out = (float*)d_out;

    char* ws = (char*)d_ws;
    short* W      = (short*)(ws);                      // 2,883,584 B
    short* A      = (short*)(ws + 2883584);            // 524,288 B
    float* bias_s = (float*)(ws + 3407872);            // 90,112 B
    float* denom  = (float*)(ws + 3497984);            // 16,384 B
    float* pi     = (float*)(ws + 3514368);            // 16,384 B
    float* tl     = (float*)(ws + 3530752);            // 16,384 B

    k_setup<<<512, 256, 0, stream>>>(
        inputs, emb, proj, mix, biases, label, sids, A, pi, tl, W, bias_s, denom);
    k_denom<<<dim3(16, 64), 256, 0, stream>>>(A, W, bias_s, denom);
    k_probs<<<dim3(16, 64), 256, 0, stream>>>(A, W, bias_s, pi, tl, denom, out);
}

// Round 16
// 81.804 us; speedup vs baseline: 4.1154x; 1.0831x over previous
//
#include <hip/hip_runtime.h>

#define ED 64
#define HD 4
#define BD 1024
#define SNEG 22222
#define NT2 1408             // 8 col-groups x 176 tiles (4 waves x 44)
#define SPAD2 22528          // NT2*16 = 256 gather blocks x 88 rows
#define SP1 (SNEG+1)         // 22223
#define LOGQ -3.81776242f    // log(-expm1(S*log1p(-1/V)))
#define LOG2E 1.44269504f

typedef short bf16x8 __attribute__((ext_vector_type(8)));
typedef float f32x4 __attribute__((ext_vector_type(4)));

static __device__ __forceinline__ short f2bf(float f) {
    union { float f; unsigned u; } v; v.f = f;
    return (short)((v.u + 0x7FFFu + ((v.u >> 16) & 1u)) >> 16);
}

static __device__ __forceinline__ float fast_tanh(float x) {
    float ax = __builtin_fabsf(x);
    float e  = __expf(-2.f * ax);
    float t  = (1.f - e) / (1.f + e);
    return __builtin_copysignf(t, x);
}

static __device__ __forceinline__ float fexp2(float x) {
#if __has_builtin(__builtin_amdgcn_exp2f)
    return __builtin_amdgcn_exp2f(x);
#else
    return __expf(x * 0.69314718f);
#endif
}

// ---------------- kernel 1: fused setup, 256 blocks ------------------------
// block: prep batches [4*blk, 4*blk+4) + gather rows [88*blk, 88*blk+88)
__global__ __launch_bounds__(256) void k_setup(
        const float* __restrict__ inputs, const float* __restrict__ emb,
        const float* __restrict__ proj,   const float* __restrict__ mix,
        const float* __restrict__ biases, const int* __restrict__ label,
        const int* __restrict__ sids,
        short* __restrict__ A, float* __restrict__ pi, float* __restrict__ tl,
        short* __restrict__ W, float* __restrict__ bias_s,
        float* __restrict__ denom) {
    const int blk = blockIdx.x, t = threadIdx.x;
    __shared__ float s_in[64];
    __shared__ float s_proj[256];
    __shared__ float s_mix[4];
    __shared__ float s_red[256];

    if (t < 16) denom[blk*16 + t] = 0.f;

    #pragma unroll 1
    for (int bi = 0; bi < 4; ++bi) {
        int b = blk*4 + bi;
        if (t < 64) s_in[t] = inputs[b*64 + t];
        __syncthreads();
        const float* pr = proj + t*64;
        float dot = 0.f;
        #pragma unroll
        for (int k = 0; k < 64; k += 4)
            dot += s_in[k]*pr[k] + s_in[k+1]*pr[k+1] + s_in[k+2]*pr[k+2] + s_in[k+3]*pr[k+3];
        float val = fast_tanh(dot);
        s_proj[t] = val;
        A[(b*4 + (t >> 6))*64 + (t & 63)] = f2bf(val * LOG2E);   // pre-scaled
        if (t < 4) {
            const float* mr = mix + t*64;
            float md = 0.f;
            for (int k = 0; k < 64; ++k) md += s_in[k]*mr[k];
            s_mix[t] = md;
        }
        int lab = label[b];
        s_red[t] = s_proj[t] * emb[(size_t)lab*64 + (t & 63)];
        __syncthreads();
        if (t < 4) {
            float m = fmaxf(fmaxf(s_mix[0], s_mix[1]), fmaxf(s_mix[2], s_mix[3]));
            float e0 = __expf(s_mix[0]-m), e1 = __expf(s_mix[1]-m);
            float e2 = __expf(s_mix[2]-m), e3 = __expf(s_mix[3]-m);
            pi[b*4 + t] = __expf(s_mix[t]-m) / (e0+e1+e2+e3);
            float sum = 0.f;
            for (int k = 0; k < 64; ++k) sum += s_red[t*64 + k];
            tl[b*4 + t] = (sum + biases[lab] - LOGQ) * LOG2E;    // base-2
        }
        __syncthreads();
    }

    // gather: 88 rows x 8 threads = 704 tasks
    #pragma unroll 1
    for (int rep = 0; rep < 3; ++rep) {
        int task = rep*256 + t;
        if (task >= 704) break;
        int s = blk*88 + (task >> 3);
        int l8 = task & 7;
        if (s < SNEG) {
            int id = sids[s];
            const float* src = emb + (size_t)id*64 + l8*8;
            bf16x8 o;
            #pragma unroll
            for (int j = 0; j < 8; ++j) o[j] = f2bf(src[j]);
            *(bf16x8*)(W + s*64 + l8*8) = o;
            if (l8 == 0) bias_s[s] = (biases[id] - LOGQ) * LOG2E;
        } else {
            bf16x8 o;
            #pragma unroll
            for (int j = 0; j < 8; ++j) o[j] = 0;
            *(bf16x8*)(W + s*64 + l8*8) = o;
            if (l8 == 0) bias_s[s] = -1e30f;   // 2^x -> 0 for pad columns
        }
    }
}

#define LOADT(S, T) { \
    const bf16x8* bp_ = (const bf16x8*)(W + (size_t)((T)*16 + c)*64); \
    b0##S = bp_[g]; b1##S = bp_[4 + g]; bb##S = bias_s[(T)*16 + c]; }

#define DCOMP(S) { \
    _Pragma("unroll") \
    for (int t4 = 0; t4 < 4; ++t4) { \
        f32x4 z = {bb##S, bb##S, bb##S, bb##S}; \
        z = __builtin_amdgcn_mfma_f32_16x16x32_bf16(a0[t4], b0##S, z, 0, 0, 0); \
        z = __builtin_amdgcn_mfma_f32_16x16x32_bf16(a1[t4], b1##S, z, 0, 0, 0); \
        s[t4*4+0] += fexp2(z[0]); \
        s[t4*4+1] += fexp2(z[1]); \
        s[t4*4+2] += fexp2(z[2]); \
        s[t4*4+3] += fexp2(z[3]); } }

#define PCOMP(S, T) { \
    int scol_ = (T)*16 + c; bool ok_ = scol_ < SNEG; \
    _Pragma("unroll") \
    for (int t4 = 0; t4 < 4; ++t4) { \
        f32x4 z = {bb##S, bb##S, bb##S, bb##S}; \
        z = __builtin_amdgcn_mfma_f32_16x16x32_bf16(a0[t4], b0##S, z, 0, 0, 0); \
        z = __builtin_amdgcn_mfma_f32_16x16x32_bf16(a1[t4], b1##S, z, 0, 0, 0); \
        float p_ = cf[t4][0]*fexp2(z[0]); \
        p_ = fmaf(cf[t4][1], fexp2(z[1]), p_); \
        p_ = fmaf(cf[t4][2], fexp2(z[2]), p_); \
        p_ = fmaf(cf[t4][3], fexp2(z[3]), p_); \
        if (ok_) orow[t4][scol_] = p_; } }

// 11-step 3-slot rotating pipeline over tiles [TB, TB+11)
#define DPIPE(TB) { \
    LOADT(A, (TB)+0) LOADT(B, (TB)+1) LOADT(C, (TB)+2) \
    DCOMP(A) LOADT(A, (TB)+3) \
    DCOMP(B) LOADT(B, (TB)+4) \
    DCOMP(C) LOADT(C, (TB)+5) \
    DCOMP(A) LOADT(A, (TB)+6) \
    DCOMP(B) LOADT(B, (TB)+7) \
    DCOMP(C) LOADT(C, (TB)+8) \
    DCOMP(A) LOADT(A, (TB)+9) \
    DCOMP(B) LOADT(B, (TB)+10) \
    DCOMP(C) \
    DCOMP(A) \
    DCOMP(B) }

#define PPIPE(TB) { \
    LOADT(A, (TB)+0) LOADT(B, (TB)+1) LOADT(C, (TB)+2) \
    PCOMP(A, (TB)+0)  LOADT(A, (TB)+3) \
    PCOMP(B, (TB)+1)  LOADT(B, (TB)+4) \
    PCOMP(C, (TB)+2)  LOADT(C, (TB)+5) \
    PCOMP(A, (TB)+3)  LOADT(A, (TB)+6) \
    PCOMP(B, (TB)+4)  LOADT(B, (TB)+7) \
    PCOMP(C, (TB)+5)  LOADT(C, (TB)+8) \
    PCOMP(A, (TB)+6)  LOADT(A, (TB)+9) \
    PCOMP(B, (TB)+7)  LOADT(B, (TB)+10) \
    PCOMP(C, (TB)+8) \
    PCOMP(A, (TB)+9) \
    PCOMP(B, (TB)+10) }

// ---------------- kernel 2: denominators, grid (8,64) = 512 blocks ---------
__global__ __launch_bounds__(256, 4) void k_denom(
        const short* __restrict__ A, const short* __restrict__ W,
        const float* __restrict__ bias_s, float* __restrict__ denom) {
    const int wave = threadIdx.x >> 6, lane = threadIdx.x & 63;
    const int g = lane >> 4, c = lane & 15;
    const int rbase = blockIdx.y * 64;
    bf16x8 a0[4], a1[4];
    #pragma unroll
    for (int t4 = 0; t4 < 4; ++t4) {
        const bf16x8* ap = (const bf16x8*)(A + (size_t)(rbase + t4*16 + c)*64);
        a0[t4] = ap[g]; a1[t4] = ap[4 + g];
    }
    float s[16];
    #pragma unroll
    for (int i = 0; i < 16; ++i) s[i] = 0.f;

    const int t0 = (blockIdx.x*4 + wave) * 44;     // 44 contiguous tiles
    bf16x8 b0A, b1A, b0B, b1B, b0C, b1C;
    float bbA, bbB, bbC;
    DPIPE(t0)
    DPIPE(t0 + 11)
    DPIPE(t0 + 22)
    DPIPE(t0 + 33)

    #pragma unroll
    for (int m = 1; m < 16; m <<= 1)
        #pragma unroll
        for (int i = 0; i < 16; ++i) s[i] += __shfl_xor(s[i], m);
    if (c == 0) {
        #pragma unroll
        for (int t4 = 0; t4 < 4; ++t4)
            #pragma unroll
            for (int r = 0; r < 4; ++r)
                atomicAdd(&denom[rbase + t4*16 + g*4 + r], s[t4*4+r]);
    }
}

// ---------------- kernel 3: probs + out[:,0] + loss, grid (8,64) -----------
__global__ __launch_bounds__(256, 4) void k_probs(
        const short* __restrict__ A, const short* __restrict__ W,
        const float* __restrict__ bias_s, const float* __restrict__ pi,
        const float* __restrict__ tl, const float* __restrict__ denom,
        float* __restrict__ out) {
    const int t = threadIdx.x;
    const int wave = t >> 6, lane = t & 63;
    const int g = lane >> 4, c = lane & 15;
    const int rbase = blockIdx.y * 64;
    __shared__ float s_cf[64];
    __shared__ float s_et[64];
    __shared__ float s_ls[4];

    if (t < 64) {
        int row = rbase + t;
        float et = fexp2(tl[row]);
        float d  = denom[row] + et;
        s_cf[t] = pi[row] / d;
        s_et[t] = et;
    }
    __syncthreads();
    if (blockIdx.x == 0 && t < 16) {
        float p0 = 0.f;
        #pragma unroll
        for (int h = 0; h < 4; ++h) p0 += s_cf[t*4 + h] * s_et[t*4 + h];
        out[(size_t)(rbase/4 + t) * SP1] = p0;
    }
    if (blockIdx.x == 0 && blockIdx.y == 0) {
        float lg = 0.f;
        for (int b = t; b < BD; b += 256) {
            float p0 = 0.f;
            #pragma unroll
            for (int h = 0; h < 4; ++h) {
                float et = fexp2(tl[b*4 + h]);
                p0 += pi[b*4 + h] / (denom[b*4 + h] + et) * et;
            }
            lg += logf(p0);
        }
        #pragma unroll
        for (int m = 1; m < 64; m <<= 1) lg += __shfl_xor(lg, m);
        if (lane == 0) s_ls[wave] = lg;
        __syncthreads();
        if (t == 0)
            out[(size_t)BD * SP1] = -(s_ls[0]+s_ls[1]+s_ls[2]+s_ls[3]) * (1.f/(float)BD);
    }

    bf16x8 a0[4], a1[4];
    float cf[4][4];
    float* orow[4];
    #pragma unroll
    for (int t4 = 0; t4 < 4; ++t4) {
        const bf16x8* ap = (const bf16x8*)(A + (size_t)(rbase + t4*16 + c)*64);
        a0[t4] = ap[g]; a1[t4] = ap[4 + g];
        #pragma unroll
        for (int r = 0; r < 4; ++r) cf[t4][r] = s_cf[t4*16 + g*4 + r];
        orow[t4] = out + (size_t)(rbase/4 + t4*4 + g) * SP1 + 1;
    }

    const int t0 = (blockIdx.x*4 + wave) * 44;
    bf16x8 b0A, b1A, b0B, b1B, b0C, b1C;
    float bbA, bbB, bbC;
    PPIPE(t0)
    PPIPE(t0 + 11)
    PPIPE(t0 + 22)
    PPIPE(t0 + 33)
}

extern "C" void kernel_launch(void* const* d_in, const int* in_sizes, int n_in,
                              void* d_out, int out_size, void* d_ws, size_t ws_size,
                              hipStream_t stream) {
    const float* inputs = (const float*)d_in[0];
    const float* emb    = (const float*)d_in[1];
    const float* proj   = (const float*)d_in[2];
    const float* mix    = (const float*)d_in[3];
    const float* biases = (const float*)d_in[4];
    const int*   label  = (const int*)d_in[5];
    const int*   sids   = (const int*)d_in[6];
    float* out = (float*)d_out;

    char* ws = (char*)d_ws;
    short* W      = (short*)(ws);                      // 2,883,584 B
    short* A      = (short*)(ws + 2883584);            // 524,288 B
    float* bias_s = (float*)(ws + 3407872);            // 90,112 B
    float* denom  = (float*)(ws + 3497984);            // 16,384 B
    float* pi     = (float*)(ws + 3514368);            // 16,384 B
    float* tl     = (float*)(ws + 3530752);            // 16,384 B

    k_setup<<<256, 256, 0, stream>>>(
        inputs, emb, proj, mix, biases, label, sids, A, pi, tl, W, bias_s, denom);
    k_denom<<<dim3(8, 64), 256, 0, stream>>>(A, W, bias_s, denom);
    k_probs<<<dim3(8, 64), 256, 0, stream>>>(A, W, bias_s, pi, tl, denom, out);
}